// Round 1
// baseline (191.010 us; speedup 1.0000x reference)
//
#include <hip/hip_runtime.h>

// Kernel 1: per-batch inclusive cumsum of durations into ws.
// One block per batch (grid-stride). L <= 4*blockDim supported.
__global__ void lr_cumsum_kernel(const int* __restrict__ dur,
                                 int* __restrict__ cum,
                                 const int* __restrict__ tlen,
                                 int BL, int BT) {
    const int T = *tlen;
    const int B = BT / T;
    const int L = BL / B;
    __shared__ int s[1024];
    for (int b = blockIdx.x; b < B; b += gridDim.x) {
        for (int i = threadIdx.x; i < L; i += blockDim.x)
            s[i] = dur[b * L + i];
        __syncthreads();
        // Hillis-Steele inclusive scan
        for (int off = 1; off < L; off <<= 1) {
            int tmp[4];
            int cnt = 0;
            for (int i = threadIdx.x; i < L; i += blockDim.x)
                tmp[cnt++] = (i >= off) ? (s[i] + s[i - off]) : s[i];
            __syncthreads();
            cnt = 0;
            for (int i = threadIdx.x; i < L; i += blockDim.x)
                s[i] = tmp[cnt++];
            __syncthreads();
        }
        for (int i = threadIdx.x; i < L; i += blockDim.x)
            cum[b * L + i] = s[i];
        __syncthreads();
    }
}

// Kernel 2: one 64-lane wave per output frame. Wave-uniform binary search
// for the phoneme index, then lane i copies float4 #i of the D-float row.
__global__ void lr_expand_kernel(const float* __restrict__ feat,
                                 const int* __restrict__ cum,
                                 const int* __restrict__ tlen,
                                 float* __restrict__ out,
                                 int BL, int BT, int D) {
    const int T = *tlen;
    const int B = BT / T;
    const int L = BL / B;

    const int wave = (int)((blockIdx.x * (size_t)blockDim.x + threadIdx.x) >> 6);
    const int lane = threadIdx.x & 63;
    if (wave >= BT) return;

    const int b = wave / T;
    const int t = wave - b * T;

    const int* __restrict__ c = cum + (size_t)b * L;
    const int total = c[L - 1];

    const int vecs = D >> 2;                       // float4s per row (D % 4 == 0)
    float4* __restrict__ orow = (float4*)(out + (size_t)wave * D);

    if (t >= total) {
        const float4 z = make_float4(0.f, 0.f, 0.f, 0.f);
        for (int i = lane; i < vecs; i += 64) orow[i] = z;
        return;
    }

    // first idx with c[idx] > t (searchsorted side='right'); t < total == c[L-1]
    int lo = 0, hi = L - 1;
    while (lo < hi) {
        const int mid = (lo + hi) >> 1;
        if (c[mid] > t) hi = mid;
        else            lo = mid + 1;
    }

    const float4* __restrict__ irow =
        (const float4*)(feat + ((size_t)b * L + lo) * (size_t)D);
    for (int i = lane; i < vecs; i += 64) orow[i] = irow[i];
}

extern "C" void kernel_launch(void* const* d_in, const int* in_sizes, int n_in,
                              void* d_out, int out_size, void* d_ws, size_t ws_size,
                              hipStream_t stream) {
    const float* feat = (const float*)d_in[0];   // [B, L, D] fp32
    const int*   dur  = (const int*)d_in[1];     // [B, L] int
    const int*   tlen = (const int*)d_in[2];     // scalar target_length (device)

    const int BL = in_sizes[1];                  // B*L
    const int D  = in_sizes[0] / in_sizes[1];    // feature dim
    const int BT = out_size / D;                 // B*T total frames

    int* cum = (int*)d_ws;                       // BL ints of scratch

    // Kernel 1: cumsum (cheap; 64 blocks grid-stride over batches)
    lr_cumsum_kernel<<<64, 256, 0, stream>>>(dur, cum, tlen, BL, BT);

    // Kernel 2: one wave per frame, 4 waves per 256-thread block
    const int waves_per_block = 256 / 64;
    const int grid = (BT + waves_per_block - 1) / waves_per_block;
    lr_expand_kernel<<<grid, 256, 0, stream>>>(feat, cum, tlen, (float*)d_out,
                                               BL, BT, D);
}

// Round 2
// 155.002 us; speedup vs baseline: 1.2323x; 1.2323x over previous
//
#include <hip/hip_runtime.h>

#define MAX_L 2048            // max phonemes per batch supported by LDS staging
#define FRAMES_PER_BLOCK 64   // output frames per block (requires T % 64 == 0)

// Kernel 1: per-batch inclusive cumsum of durations into ws (tiny).
__global__ void lr_cumsum_kernel(const int* __restrict__ dur,
                                 int* __restrict__ cum,
                                 const int* __restrict__ tlen,
                                 int BL, int BT) {
    const int T = *tlen;
    const int B = BT / T;
    const int L = BL / B;
    __shared__ int s[MAX_L];
    for (int b = blockIdx.x; b < B; b += gridDim.x) {
        for (int i = threadIdx.x; i < L; i += blockDim.x)
            s[i] = dur[b * L + i];
        __syncthreads();
        for (int off = 1; off < L; off <<= 1) {
            int tmp[MAX_L / 256];
            int c = 0;
            for (int i = threadIdx.x; i < L; i += blockDim.x)
                tmp[c++] = (i >= off) ? (s[i] + s[i - off]) : s[i];
            __syncthreads();
            c = 0;
            for (int i = threadIdx.x; i < L; i += blockDim.x)
                s[i] = tmp[c++];
            __syncthreads();
        }
        for (int i = threadIdx.x; i < L; i += blockDim.x)
            cum[b * L + i] = s[i];
        __syncthreads();
    }
}

// Kernel 2: one block per 64 frames of one batch.
//  - cum row staged in LDS once per block (kills the global binary-search chain)
//  - 64 threads search in LDS -> sidx[64]
//  - each wave copies 16 frames; lane i moves float4 #i of the row.
//    16 independent load->store pairs per lane => MLP hides L1/L2 latency.
__global__ __launch_bounds__(256) void lr_expand_kernel(
        const float* __restrict__ feat,
        const int* __restrict__ cum,
        const int* __restrict__ tlen,
        float* __restrict__ out,
        int BL, int BT, int D) {
    const int T = *tlen;
    const int B = BT / T;
    const int L = BL / B;
    const int vecs = D >> 2;  // float4s per row

    __shared__ int sc[MAX_L];
    __shared__ int sidx[FRAMES_PER_BLOCK];

    const int frame_base = blockIdx.x * FRAMES_PER_BLOCK;
    if (frame_base >= BT) return;
    const int b = frame_base / T;        // tile never crosses batch (T % 64 == 0)
    const int t0 = frame_base - b * T;   // first in-batch frame of this tile

    const int* __restrict__ crow = cum + (size_t)b * L;
    for (int i = threadIdx.x; i < L; i += blockDim.x)
        sc[i] = crow[i];
    __syncthreads();

    const int total = sc[L - 1];

    if (threadIdx.x < FRAMES_PER_BLOCK) {
        const int t = t0 + threadIdx.x;
        int p = -1;
        if (t < total && frame_base + threadIdx.x < BT) {
            int lo = 0, hi = L - 1;
            while (lo < hi) {
                const int mid = (lo + hi) >> 1;
                if (sc[mid] > t) hi = mid;
                else             lo = mid + 1;
            }
            p = lo;
        }
        sidx[threadIdx.x] = p;
    }
    __syncthreads();

    const int wv   = threadIdx.x >> 6;
    const int lane = threadIdx.x & 63;
    const int fpw  = FRAMES_PER_BLOCK / 4;  // frames per wave = 16

    const float4* __restrict__ fbase = (const float4*)(feat + (size_t)b * L * D);
    float4* __restrict__ obase = (float4*)(out + (size_t)frame_base * D);
    const float4 z = make_float4(0.f, 0.f, 0.f, 0.f);

#pragma unroll 4
    for (int j = 0; j < fpw; ++j) {
        const int f = wv * fpw + j;
        if (frame_base + f >= BT) continue;
        const int p = sidx[f];
        float4* __restrict__ orow = obase + (size_t)f * vecs;
        if (p >= 0) {
            const float4* __restrict__ irow = fbase + (size_t)p * vecs;
            for (int i = lane; i < vecs; i += 64)
                orow[i] = irow[i];
        } else {
            for (int i = lane; i < vecs; i += 64)
                orow[i] = z;
        }
    }
}

extern "C" void kernel_launch(void* const* d_in, const int* in_sizes, int n_in,
                              void* d_out, int out_size, void* d_ws, size_t ws_size,
                              hipStream_t stream) {
    const float* feat = (const float*)d_in[0];   // [B, L, D] fp32
    const int*   dur  = (const int*)d_in[1];     // [B, L] int32
    const int*   tlen = (const int*)d_in[2];     // scalar target_length (device)

    const int BL = in_sizes[1];                  // B*L
    const int D  = in_sizes[0] / in_sizes[1];    // feature dim
    const int BT = out_size / D;                 // B*T total frames

    int* cum = (int*)d_ws;                       // BL ints of scratch

    lr_cumsum_kernel<<<64, 256, 0, stream>>>(dur, cum, tlen, BL, BT);

    const int grid = (BT + FRAMES_PER_BLOCK - 1) / FRAMES_PER_BLOCK;
    lr_expand_kernel<<<grid, 256, 0, stream>>>(feat, cum, tlen, (float*)d_out,
                                               BL, BT, D);
}

// Round 3
// 147.806 us; speedup vs baseline: 1.2923x; 1.0487x over previous
//
#include <hip/hip_runtime.h>

#define MAX_L 2048            // max phonemes per batch supported by LDS staging
#define MAX_EPC 8             // max cum elements per thread (L <= 256*8)
#define FRAMES_PER_BLOCK 64   // output frames per block (requires T % 64 == 0)

// Fused length-regulator: one 256-thread block per 64 output frames.
//  - block re-computes its batch's duration cumsum in LDS (shuffle scan,
//    2 barriers, registers only — no scratch)
//  - 64 threads binary-search in LDS -> sidx[64]
//  - each wave copies 16 frames; specialization for D==256 gives 16
//    independent float4 load->store pairs per lane (full MLP).
__global__ __launch_bounds__(256, 3) void lr_fused_kernel(
        const float* __restrict__ feat,
        const int* __restrict__ dur,
        const int* __restrict__ tlen,
        float* __restrict__ out,
        int BL, int BT, int D) {
    const int T = *tlen;
    const int B = BT / T;
    const int L = BL / B;
    const int vecs = D >> 2;                 // float4s per row

    __shared__ int sc[MAX_L];                // inclusive cumsum of durations
    __shared__ int swsum[4];                 // per-wave chunk sums
    __shared__ int sidx[FRAMES_PER_BLOCK];   // phoneme index per frame (-1 = zero)

    const int frame_base = blockIdx.x * FRAMES_PER_BLOCK;
    if (frame_base >= BT) return;
    const int b  = frame_base / T;           // tile never crosses batch (T%64==0)
    const int t0 = frame_base - b * T;

    const int tid  = threadIdx.x;
    const int lane = tid & 63;
    const int wv   = tid >> 6;

    // ---- per-block cumsum of this batch's duration row ----
    const int epc  = (L + blockDim.x - 1) / blockDim.x;   // elems per thread
    const int base = tid * epc;
    const int* __restrict__ drow = dur + (size_t)b * L;

    int local[MAX_EPC];
    int run = 0;
#pragma unroll
    for (int e = 0; e < MAX_EPC; ++e) {
        int v = 0;
        if (e < epc && base + e < L) v = drow[base + e];
        run += v;
        local[e] = run;                      // inclusive within chunk
    }
    // inclusive shuffle-scan of chunk sums across the 64-lane wave
    int ws = run;
#pragma unroll
    for (int off = 1; off < 64; off <<= 1) {
        int up = __shfl_up(ws, off, 64);
        if (lane >= off) ws += up;
    }
    if (lane == 63) swsum[wv] = ws;
    __syncthreads();
    int wprefix = 0;
    for (int w = 0; w < wv; ++w) wprefix += swsum[w];
    const int chunk_prefix = wprefix + ws - run;   // exclusive prefix of this chunk
#pragma unroll
    for (int e = 0; e < MAX_EPC; ++e) {
        if (e < epc && base + e < L) sc[base + e] = chunk_prefix + local[e];
    }
    __syncthreads();

    const int total = sc[L - 1];

    // ---- searchsorted(side='right') in LDS for this block's 64 frames ----
    if (tid < FRAMES_PER_BLOCK) {
        const int t = t0 + tid;
        int p = -1;
        if (t < total && frame_base + tid < BT) {
            int lo = 0, hi = L - 1;
            while (lo < hi) {
                const int mid = (lo + hi) >> 1;
                if (sc[mid] > t) hi = mid;
                else             lo = mid + 1;
            }
            p = lo;
        }
        sidx[tid] = p;
    }
    __syncthreads();

    // ---- copy: each wave moves 16 frames ----
    const float4 z = make_float4(0.f, 0.f, 0.f, 0.f);

    if (vecs == 64) {
        // Fast path (D == 256): lane i moves float4 #i of each frame.
        const float4* __restrict__ fb = (const float4*)(feat + (size_t)b * L * D);
        float4* __restrict__ ob = (float4*)(out + (size_t)frame_base * D);
#pragma unroll
        for (int j = 0; j < 16; ++j) {
            const int f  = wv * 16 + j;
            const int pj = sidx[f];
            float4 v = z;
            if (pj >= 0) v = fb[(size_t)pj * 64 + lane];
            ob[(size_t)f * 64 + lane] = v;
        }
    } else {
        // Generic fallback
        const float4* __restrict__ fb = (const float4*)(feat + (size_t)b * L * D);
        float4* __restrict__ ob = (float4*)(out + (size_t)frame_base * D);
        for (int j = 0; j < 16; ++j) {
            const int f = wv * 16 + j;
            if (frame_base + f >= BT) continue;
            const int pj = sidx[f];
            float4* __restrict__ orow = ob + (size_t)f * vecs;
            if (pj >= 0) {
                const float4* __restrict__ irow = fb + (size_t)pj * vecs;
                for (int i = lane; i < vecs; i += 64) orow[i] = irow[i];
            } else {
                for (int i = lane; i < vecs; i += 64) orow[i] = z;
            }
        }
    }
}

extern "C" void kernel_launch(void* const* d_in, const int* in_sizes, int n_in,
                              void* d_out, int out_size, void* d_ws, size_t ws_size,
                              hipStream_t stream) {
    const float* feat = (const float*)d_in[0];   // [B, L, D] fp32
    const int*   dur  = (const int*)d_in[1];     // [B, L] int32
    const int*   tlen = (const int*)d_in[2];     // scalar target_length (device)

    const int BL = in_sizes[1];                  // B*L
    const int D  = in_sizes[0] / in_sizes[1];    // feature dim
    const int BT = out_size / D;                 // B*T total frames

    const int grid = (BT + FRAMES_PER_BLOCK - 1) / FRAMES_PER_BLOCK;
    lr_fused_kernel<<<grid, 256, 0, stream>>>(feat, dur, tlen, (float*)d_out,
                                              BL, BT, D);
}